// Round 14
// baseline (789.652 us; speedup 1.0000x reference)
//
#include <hip/hip_runtime.h>
#include <hip/hip_bf16.h>
#include <stdint.h>

#define T_NUM 1024
#define H_DIM 2048
#define E_NUM 16
#define TOPK 4
#define I_DIM 1408
#define SHI_DIM 2816

typedef __attribute__((ext_vector_type(4))) float f32x4;
typedef __attribute__((ext_vector_type(8))) short bf16x8;
typedef __attribute__((ext_vector_type(4))) short s16x4;

static __device__ __forceinline__ short f2bf(float f) {
    __hip_bfloat16 h = __float2bfloat16(f);
    return __builtin_bit_cast(short, h);
}
static __device__ __forceinline__ float bf2f(short s) {
    return __bfloat162float(__builtin_bit_cast(__hip_bfloat16, s));
}

// ---------------- router: fp32 logits -> softmax -> top4 (+ x -> bf16) ------
__global__ void router_kernel(const float* __restrict__ x, const float* __restrict__ wgate,
                              int* __restrict__ top_e, float* __restrict__ top_w,
                              short* __restrict__ xb) {
    const int t = blockIdx.x;
    const int tid = threadIdx.x;       // 256 threads
    __shared__ float xsh[H_DIM];
    const float* xr = x + (size_t)t * H_DIM;
    for (int h = tid; h < H_DIM; h += 256) xsh[h] = xr[h];
    __syncthreads();

    {   // bf16 copy of x
        short v[8];
        #pragma unroll
        for (int i = 0; i < 8; ++i) v[i] = f2bf(xsh[tid * 8 + i]);
        *reinterpret_cast<bf16x8*>(xb + (size_t)t * H_DIM + tid * 8) = *(bf16x8*)v;
    }

    const int e = tid >> 4;            // 0..15
    const int j = tid & 15;
    const float* wr = wgate + (size_t)e * H_DIM;
    float acc = 0.f;
    for (int h = j; h < H_DIM; h += 16) acc += xsh[h] * wr[h];
    #pragma unroll
    for (int m = 8; m >= 1; m >>= 1) acc += __shfl_down(acc, m, 16);

    __shared__ float logits[E_NUM];
    if (j == 0) logits[e] = acc;
    __syncthreads();

    if (tid == 0) {
        float mx = logits[0];
        #pragma unroll
        for (int i = 1; i < E_NUM; ++i) mx = fmaxf(mx, logits[i]);
        float p[E_NUM]; float s = 0.f;
        #pragma unroll
        for (int i = 0; i < E_NUM; ++i) { p[i] = expf(logits[i] - mx); s += p[i]; }
        const float inv = 1.f / s;
        #pragma unroll
        for (int i = 0; i < E_NUM; ++i) p[i] *= inv;
        for (int k = 0; k < TOPK; ++k) {
            float best = -1.f; int bi = 0;
            #pragma unroll
            for (int i = 0; i < E_NUM; ++i) if (p[i] > best) { best = p[i]; bi = i; }
            top_e[t * TOPK + k] = bi;
            top_w[t * TOPK + k] = best;
            p[bi] = -2.f;
        }
    }
}

// ------- stable bucket sort of 4096 slots by expert (deterministic) -------
__global__ void perm_kernel(const int* __restrict__ top_e,
                            int* __restrict__ offs, int* __restrict__ perm) {
    __shared__ int cnt[256][E_NUM];
    __shared__ int base[E_NUM];
    const int tid = threadIdx.x;
    int c[E_NUM];
    #pragma unroll
    for (int i = 0; i < E_NUM; ++i) c[i] = 0;
    for (int s = tid * 16; s < tid * 16 + 16; ++s) c[top_e[s]]++;
    #pragma unroll
    for (int i = 0; i < E_NUM; ++i) cnt[tid][i] = c[i];
    __syncthreads();
    if (tid < E_NUM) {
        int run = 0;
        for (int b = 0; b < 256; ++b) { int v = cnt[b][tid]; cnt[b][tid] = run; run += v; }
        base[tid] = run;
    }
    __syncthreads();
    if (tid == 0) {
        int run = 0;
        for (int e2 = 0; e2 < E_NUM; ++e2) { int v = base[e2]; base[e2] = run; offs[e2] = run; run += v; }
        offs[E_NUM] = run;
    }
    __syncthreads();
    int run[E_NUM];
    #pragma unroll
    for (int i = 0; i < E_NUM; ++i) run[i] = base[i] + cnt[tid][i];
    for (int s = tid * 16; s < tid * 16 + 16; ++s) {
        int e2 = top_e[s];
        perm[run[e2]++] = s;
    }
}

// ------- final combine: out[t][h] += sum_k dr[4t+k][h]  (dr pre-weighted) -------
__global__ void combine_kernel(const short* __restrict__ dr, float* __restrict__ out) {
    const int i = blockIdx.x * 256 + threadIdx.x;   // one per 8 cols of a token
    const int t = i >> 8;                            // H_DIM/8 = 256
    const int h8 = (i & 255) * 8;
    float s[8];
    f32x4 o0 = *reinterpret_cast<const f32x4*>(out + (size_t)t * H_DIM + h8);
    f32x4 o1 = *reinterpret_cast<const f32x4*>(out + (size_t)t * H_DIM + h8 + 4);
    #pragma unroll
    for (int j = 0; j < 4; ++j) { s[j] = o0[j]; s[4 + j] = o1[j]; }
    #pragma unroll
    for (int k = 0; k < TOPK; ++k) {
        bf16x8 v = *reinterpret_cast<const bf16x8*>(dr + ((size_t)(t * TOPK + k)) * H_DIM + h8);
        #pragma unroll
        for (int j = 0; j < 8; ++j) s[j] += bf2f(v[j]);
    }
    f32x4 r0 = { s[0], s[1], s[2], s[3] };
    f32x4 r1 = { s[4], s[5], s[6], s[7] };
    *reinterpret_cast<f32x4*>(out + (size_t)t * H_DIM + h8) = r0;
    *reinterpret_cast<f32x4*>(out + (size_t)t * H_DIM + h8 + 4) = r1;
}

// ---- NB=2 gate+up GEMM (R1 engine, bf16 A): 128M x 128N x 32K, 2 blocks/CU ----
// A bf16 [rows][2048]; B1=gate, B2=up f32 [2048][LDN]; out = silu(g)*u bf16.
// MODE 0: routed (A gathered via perm; out row = slot). MODE 1: shared (dense).
template<int MODE>
__global__ __launch_bounds__(256, 2) void gemm_gu2(
    const short* __restrict__ A,
    const float* __restrict__ B1g, const float* __restrict__ B2g, int ldb,
    short* __restrict__ Act,
    const int* __restrict__ perm, const int* __restrict__ offs,
    int nmt, int nnt)
{
    constexpr int KP = 40;
    __shared__ short As[2][128 * KP];          // 20 KB
    __shared__ short Bs[2][2 * 128 * KP];      // 40 KB
    __shared__ int   rows_a[128];
    __shared__ int   rows_o[128];

    const int tid = threadIdx.x;

    int wg = blockIdx.x;
    {
        const int nwg = gridDim.x;
        const int qq = nwg >> 3, rr = nwg & 7;
        const int xcd = wg & 7, lin = wg >> 3;
        wg = (xcd < rr ? xcd * (qq + 1) : rr * (qq + 1) + (xcd - rr) * qq) + lin;
    }
    const int mt = wg % nmt;
    const int nt = (wg / nmt) % nnt;
    const int e  = wg / (nmt * nnt);

    int off = 0, cnt = T_NUM;
    const float* B1 = B1g;
    const float* B2 = B2g;
    if constexpr (MODE == 0) {
        off = offs[e]; cnt = offs[e + 1] - off;
        if (mt * 128 >= cnt) return;
        B1 = B1g + (size_t)e * H_DIM * I_DIM;
        B2 = B2g + (size_t)e * H_DIM * I_DIM;
    }

    if (tid < 128) {
        const int gm = mt * 128 + tid;
        if constexpr (MODE == 0) {
            int s = perm[off + (gm < cnt ? gm : cnt - 1)];
            rows_a[tid] = s >> 2; rows_o[tid] = s;
        } else {
            rows_a[tid] = gm; rows_o[tid] = gm;
        }
    }
    __syncthreads();

    int raReg[2];
    #pragma unroll
    for (int it = 0; it < 2; ++it) raReg[it] = rows_a[it * 64 + (tid >> 2)];

    bf16x8 aReg[2];
    float  bReg[2][4][4];

    auto gload = [&](int kt) {
        const int k0 = kt * 32;
        #pragma unroll
        for (int it = 0; it < 2; ++it) {
            const int q = it * 256 + tid;
            const int ko = (q & 3) * 8;
            aReg[it] = *reinterpret_cast<const bf16x8*>(A + (size_t)raReg[it] * H_DIM + k0 + ko);
        }
        #pragma unroll
        for (int it = 0; it < 4; ++it) {
            const int q = it * 256 + tid;
            const int n = q & 127, kb = (q >> 7) * 4;
            const float* p1 = B1 + (size_t)(k0 + kb) * ldb + (size_t)nt * 128 + n;
            #pragma unroll
            for (int dk = 0; dk < 4; ++dk) bReg[0][it][dk] = p1[(size_t)dk * ldb];
            const float* p2 = B2 + (size_t)(k0 + kb) * ldb + (size_t)nt * 128 + n;
            #pragma unroll
            for (int dk = 0; dk < 4; ++dk) bReg[1][it][dk] = p2[(size_t)dk * ldb];
        }
    };

    auto swrite = [&](int buf) {
        #pragma unroll
        for (int it = 0; it < 2; ++it) {
            const int q = it * 256 + tid;
            const int m = q >> 2, ko = (q & 3) * 8;
            *reinterpret_cast<bf16x8*>(&As[buf][m * KP + ko]) = aReg[it];
        }
        #pragma unroll
        for (int it = 0; it < 4; ++it) {
            const int q = it * 256 + tid;
            const int n = q & 127, kb = (q >> 7) * 4;
            #pragma unroll
            for (int mat = 0; mat < 2; ++mat) {
                s16x4 v = { f2bf(bReg[mat][it][0]), f2bf(bReg[mat][it][1]),
                            f2bf(bReg[mat][it][2]), f2bf(bReg[mat][it][3]) };
                *reinterpret_cast<s16x4*>(&Bs[buf][(mat * 128 + n) * KP + kb]) = v;
            }
        }
    };

    f32x4 acc1[4][4], acc2[4][4];
    #pragma unroll
    for (int i = 0; i < 4; ++i)
        #pragma unroll
        for (int j = 0; j < 4; ++j) { acc1[i][j] = (f32x4)0.f; acc2[i][j] = (f32x4)0.f; }

    const int lane = tid & 63;
    const int wr = (tid >> 6) >> 1, wc = (tid >> 6) & 1;
    const int lrow = lane & 15;
    const int lko = (lane >> 4) * 8;

    auto compute = [&](int buf) {
        bf16x8 af[4];
        #pragma unroll
        for (int mi = 0; mi < 4; ++mi)
            af[mi] = *reinterpret_cast<const bf16x8*>(&As[buf][(wr * 64 + mi * 16 + lrow) * KP + lko]);
        #pragma unroll
        for (int ni = 0; ni < 4; ++ni) {
            const int brow = (wc * 64 + ni * 16 + lrow) * KP + lko;
            bf16x8 b1 = *reinterpret_cast<const bf16x8*>(&Bs[buf][brow]);
            #pragma unroll
            for (int mi = 0; mi < 4; ++mi)
                acc1[mi][ni] = __builtin_amdgcn_mfma_f32_16x16x32_bf16(af[mi], b1, acc1[mi][ni], 0, 0, 0);
            bf16x8 b2 = *reinterpret_cast<const bf16x8*>(&Bs[buf][128 * KP + brow]);
            #pragma unroll
            for (int mi = 0; mi < 4; ++mi)
                acc2[mi][ni] = __builtin_amdgcn_mfma_f32_16x16x32_bf16(af[mi], b2, acc2[mi][ni], 0, 0, 0);
        }
    };

    const int NK = H_DIM / 32;
    gload(0);
    int cur = 0;
    for (int kt = 0; kt < NK; ++kt) {
        swrite(cur);
        __syncthreads();
        if (kt + 1 < NK) gload(kt + 1);
        compute(cur);
        cur ^= 1;
    }

    #pragma unroll
    for (int mi = 0; mi < 4; ++mi) {
        #pragma unroll
        for (int j = 0; j < 4; ++j) {
            const int ml = wr * 64 + mi * 16 + (lane >> 4) * 4 + j;
            const int gm = mt * 128 + ml;
            if constexpr (MODE == 0) { if (gm >= cnt) continue; }
            const int orow = rows_o[ml];
            #pragma unroll
            for (int ni = 0; ni < 4; ++ni) {
                const int n = nt * 128 + wc * 64 + ni * 16 + (lane & 15);
                const float g = acc1[mi][ni][j];
                const float u = acc2[mi][ni][j];
                Act[(size_t)orow * ldb + n] = f2bf(g / (1.f + __expf(-g)) * u);
            }
        }
    }
}

// ---- ND=2 down GEMM: 128M x 256N x 32K, 2 blocks/CU (same load pattern) ----
// A bf16 [rows][KD]; B f32 [KD][2048].
// MODE 2: routed (A=act_r gathered; dr[slot] = w*v bf16). MODE 3: shared (f32 out).
template<int MODE>
__global__ __launch_bounds__(256, 2) void gemm_dn2(
    const short* __restrict__ A,
    const float* __restrict__ B_,
    void* __restrict__ Outv,
    const int* __restrict__ perm, const int* __restrict__ offs,
    const float* __restrict__ top_w, int nmt, int nnt)
{
    constexpr int KD = (MODE == 2) ? I_DIM : SHI_DIM;
    constexpr int KP = 40;
    __shared__ short As[2][128 * KP];      // 20 KB
    __shared__ short Bs[2][256 * KP];      // 40 KB
    __shared__ int   rows_a[128];
    __shared__ int   rows_o[128];
    __shared__ float w_m[128];

    const int tid = threadIdx.x;

    int wg = blockIdx.x;
    {
        const int nwg = gridDim.x;
        const int qq = nwg >> 3, rr = nwg & 7;
        const int xcd = wg & 7, lin = wg >> 3;
        wg = (xcd < rr ? xcd * (qq + 1) : rr * (qq + 1) + (xcd - rr) * qq) + lin;
    }
    const int mt = wg % nmt;
    const int nt = (wg / nmt) % nnt;
    const int e  = wg / (nmt * nnt);

    int off = 0, cnt = T_NUM;
    const float* B = B_;
    if constexpr (MODE == 2) {
        off = offs[e]; cnt = offs[e + 1] - off;
        if (mt * 128 >= cnt) return;
        B = B_ + (size_t)e * I_DIM * H_DIM;
    }
    const int ncol = nt * 256;

    if (tid < 128) {
        const int gm = mt * 128 + tid;
        if constexpr (MODE == 2) {
            int s = perm[off + (gm < cnt ? gm : cnt - 1)];
            rows_a[tid] = s; rows_o[tid] = s; w_m[tid] = top_w[s];
        } else {
            rows_a[tid] = gm; rows_o[tid] = gm; w_m[tid] = 1.f;
        }
    }
    __syncthreads();

    int raReg[2];
    #pragma unroll
    for (int it = 0; it < 2; ++it) raReg[it] = rows_a[it * 64 + (tid >> 2)];

    bf16x8 aReg[2];
    float  bReg[8][4];

    auto gload = [&](int kt) {
        const int k0 = kt * 32;
        #pragma unroll
        for (int it = 0; it < 2; ++it) {
            const int q = it * 256 + tid;
            const int ko = (q & 3) * 8;
            aReg[it] = *reinterpret_cast<const bf16x8*>(A + (size_t)raReg[it] * KD + k0 + ko);
        }
        #pragma unroll
        for (int it = 0; it < 8; ++it) {
            const int q = it * 256 + tid;
            const int n = q & 255, kb = (q >> 8) * 4;
            const float* p1 = B + (size_t)(k0 + kb) * H_DIM + ncol + n;
            #pragma unroll
            for (int dk = 0; dk < 4; ++dk) bReg[it][dk] = p1[(size_t)dk * H_DIM];
        }
    };

    auto swrite = [&](int buf) {
        #pragma unroll
        for (int it = 0; it < 2; ++it) {
            const int q = it * 256 + tid;
            const int m = q >> 2, ko = (q & 3) * 8;
            *reinterpret_cast<bf16x8*>(&As[buf][m * KP + ko]) = aReg[it];
        }
        #pragma unroll
        for (int it = 0; it < 8; ++it) {
            const int q = it * 256 + tid;
            const int n = q & 255, kb = (q >> 8) * 4;
            s16x4 v = { f2bf(bReg[it][0]), f2bf(bReg[it][1]), f2bf(bReg[it][2]), f2bf(bReg[it][3]) };
            *reinterpret_cast<s16x4*>(&Bs[buf][n * KP + kb]) = v;
        }
    };

    f32x4 acc[4][8];
    #pragma unroll
    for (int i = 0; i < 4; ++i)
        #pragma unroll
        for (int j = 0; j < 8; ++j) acc[i][j] = (f32x4)0.f;

    const int lane = tid & 63;
    const int wr = (tid >> 6) >> 1, wc = (tid >> 6) & 1;   // 2x2 waves: 64M x 128N each
    const int lrow = lane & 15;
    const int lko = (lane >> 4) * 8;

    auto compute = [&](int buf) {
        bf16x8 af[4];
        #pragma unroll
        for (int mi = 0; mi < 4; ++mi)
            af[mi] = *reinterpret_cast<const bf16x8*>(&As[buf][(wr * 64 + mi * 16 + lrow) * KP + lko]);
        #pragma unroll
        for (int ni = 0; ni < 8; ++ni) {
            bf16x8 bfr = *reinterpret_cast<const bf16x8*>(&Bs[buf][(wc * 128 + ni * 16 + lrow) * KP + lko]);
            #pragma unroll
            for (int mi = 0; mi < 4; ++mi)
                acc[mi][ni] = __builtin_amdgcn_mfma_f32_16x16x32_bf16(af[mi], bfr, acc[mi][ni], 0, 0, 0);
        }
    };

    const int NK = KD / 32;
    gload(0);
    int cur = 0;
    for (int kt = 0; kt < NK; ++kt) {
        swrite(cur);
        __syncthreads();
        if (kt + 1 < NK) gload(kt + 1);
        compute(cur);
        cur ^= 1;
    }

    #pragma unroll
    for (int mi = 0; mi < 4; ++mi) {
        #pragma unroll
        for (int j = 0; j < 4; ++j) {
            const int ml = wr * 64 + mi * 16 + (lane >> 4) * 4 + j;
            const int gm = mt * 128 + ml;
            if constexpr (MODE == 2) { if (gm >= cnt) continue; }
            const int orow = rows_o[ml];
            const float wsc = w_m[ml];
            #pragma unroll
            for (int ni = 0; ni < 8; ++ni) {
                const int n = ncol + wc * 128 + ni * 16 + (lane & 15);
                const float v = acc[mi][ni][j];
                if constexpr (MODE == 2) {
                    ((short*)Outv)[(size_t)orow * H_DIM + n] = f2bf(v * wsc);
                } else {
                    ((float*)Outv)[(size_t)orow * H_DIM + n] = v;
                }
            }
        }
    }
}

extern "C" void kernel_launch(void* const* d_in, const int* in_sizes, int n_in,
                              void* d_out, int out_size, void* d_ws, size_t ws_size,
                              hipStream_t stream) {
    const float* x     = (const float*)d_in[0];
    const float* wgate = (const float*)d_in[1];
    const float* wg    = (const float*)d_in[2];
    const float* wu    = (const float*)d_in[3];
    const float* wd    = (const float*)d_in[4];
    const float* sg    = (const float*)d_in[5];
    const float* su    = (const float*)d_in[6];
    const float* sd    = (const float*)d_in[7];
    float* out = (float*)d_out;

    uintptr_t p = (uintptr_t)d_ws;
    auto alloc = [&](size_t bytes) {
        p = (p + 255) & ~(uintptr_t)255;
        void* r = (void*)p; p += bytes; return r;
    };
    int*   top_e = (int*)alloc((size_t)T_NUM * TOPK * sizeof(int));
    float* top_w = (float*)alloc((size_t)T_NUM * TOPK * sizeof(float));
    int*   offs  = (int*)alloc((E_NUM + 1) * sizeof(int));
    int*   perm  = (int*)alloc((size_t)T_NUM * TOPK * sizeof(int));
    short* xb    = (short*)alloc((size_t)T_NUM * H_DIM * 2);
    short* act_r = (short*)alloc((size_t)T_NUM * TOPK * I_DIM * 2);   // 11.5 MB
    short* act_s = (short*)alloc((size_t)T_NUM * SHI_DIM * 2);        // 5.8 MB
    short* dr    = (short*)alloc((size_t)T_NUM * TOPK * H_DIM * 2);   // 16.8 MB

    router_kernel<<<T_NUM, 256, 0, stream>>>(x, wgate, top_e, top_w, xb);
    perm_kernel<<<1, 256, 0, stream>>>(top_e, offs, perm);

    const int nmtT = T_NUM / 128;    // 8

    // shared gate+up+silu (fused): grid 8 * 22 = 176
    gemm_gu2<1><<<nmtT * (SHI_DIM / 128), 256, 0, stream>>>(
        xb, sg, su, SHI_DIM, act_s, nullptr, nullptr, nmtT, SHI_DIM / 128);
    // shared down -> out f32 (plain stores init out): grid 8 * 8 = 64
    gemm_dn2<3><<<nmtT * (H_DIM / 256), 256, 0, stream>>>(
        act_s, sd, out, nullptr, nullptr, nullptr, nmtT, H_DIM / 256);

    // routed gate+up+silu per expert: grid 8 * 11 * 16 = 1408
    gemm_gu2<0><<<nmtT * (I_DIM / 128) * E_NUM, 256, 0, stream>>>(
        xb, wg, wu, I_DIM, act_r, perm, offs, nmtT, I_DIM / 128);
    // routed down per expert -> dr: grid 8 * 8 * 16 = 1024
    gemm_dn2<2><<<nmtT * (H_DIM / 256) * E_NUM, 256, 0, stream>>>(
        act_r, wd, dr, perm, offs, top_w, nmtT, H_DIM / 256);
    // out[t] += sum_k dr[4t+k]
    combine_kernel<<<T_NUM * H_DIM / 8 / 256, 256, 0, stream>>>(dr, out);
}

// Round 15
// 610.574 us; speedup vs baseline: 1.2933x; 1.2933x over previous
//
#include <hip/hip_runtime.h>
#include <hip/hip_bf16.h>
#include <stdint.h>

#define T_NUM 1024
#define H_DIM 2048
#define E_NUM 16
#define TOPK 4
#define I_DIM 1408
#define SHI_DIM 2816

typedef __attribute__((ext_vector_type(4))) float f32x4;
typedef __attribute__((ext_vector_type(8))) short bf16x8;
typedef __attribute__((ext_vector_type(4))) short s16x4;

static __device__ __forceinline__ short f2bf(float f) {
    __hip_bfloat16 h = __float2bfloat16(f);
    return __builtin_bit_cast(short, h);
}
static __device__ __forceinline__ float bf2f(short s) {
    return __bfloat162float(__builtin_bit_cast(__hip_bfloat16, s));
}

// ---------------- router: fp32 logits -> softmax -> top4 (+ x -> bf16) ------
__global__ void router_kernel(const float* __restrict__ x, const float* __restrict__ wgate,
                              int* __restrict__ top_e, float* __restrict__ top_w,
                              short* __restrict__ xb) {
    const int t = blockIdx.x;
    const int tid = threadIdx.x;       // 256 threads
    __shared__ float xsh[H_DIM];
    const float* xr = x + (size_t)t * H_DIM;
    for (int h = tid; h < H_DIM; h += 256) xsh[h] = xr[h];
    __syncthreads();

    {   // bf16 copy of x
        short v[8];
        #pragma unroll
        for (int i = 0; i < 8; ++i) v[i] = f2bf(xsh[tid * 8 + i]);
        *reinterpret_cast<bf16x8*>(xb + (size_t)t * H_DIM + tid * 8) = *(bf16x8*)v;
    }

    const int e = tid >> 4;            // 0..15
    const int j = tid & 15;
    const float* wr = wgate + (size_t)e * H_DIM;
    float acc = 0.f;
    for (int h = j; h < H_DIM; h += 16) acc += xsh[h] * wr[h];
    #pragma unroll
    for (int m = 8; m >= 1; m >>= 1) acc += __shfl_down(acc, m, 16);

    __shared__ float logits[E_NUM];
    if (j == 0) logits[e] = acc;
    __syncthreads();

    if (tid == 0) {
        float mx = logits[0];
        #pragma unroll
        for (int i = 1; i < E_NUM; ++i) mx = fmaxf(mx, logits[i]);
        float p[E_NUM]; float s = 0.f;
        #pragma unroll
        for (int i = 0; i < E_NUM; ++i) { p[i] = expf(logits[i] - mx); s += p[i]; }
        const float inv = 1.f / s;
        #pragma unroll
        for (int i = 0; i < E_NUM; ++i) p[i] *= inv;
        for (int k = 0; k < TOPK; ++k) {
            float best = -1.f; int bi = 0;
            #pragma unroll
            for (int i = 0; i < E_NUM; ++i) if (p[i] > best) { best = p[i]; bi = i; }
            top_e[t * TOPK + k] = bi;
            top_w[t * TOPK + k] = best;
            p[bi] = -2.f;
        }
    }
}

// ------- stable bucket sort of 4096 slots by expert (deterministic) -------
__global__ void perm_kernel(const int* __restrict__ top_e,
                            int* __restrict__ offs, int* __restrict__ perm) {
    __shared__ int cnt[256][E_NUM];
    __shared__ int base[E_NUM];
    const int tid = threadIdx.x;
    int c[E_NUM];
    #pragma unroll
    for (int i = 0; i < E_NUM; ++i) c[i] = 0;
    for (int s = tid * 16; s < tid * 16 + 16; ++s) c[top_e[s]]++;
    #pragma unroll
    for (int i = 0; i < E_NUM; ++i) cnt[tid][i] = c[i];
    __syncthreads();
    if (tid < E_NUM) {
        int run = 0;
        for (int b = 0; b < 256; ++b) { int v = cnt[b][tid]; cnt[b][tid] = run; run += v; }
        base[tid] = run;
    }
    __syncthreads();
    if (tid == 0) {
        int run = 0;
        for (int e2 = 0; e2 < E_NUM; ++e2) { int v = base[e2]; base[e2] = run; offs[e2] = run; run += v; }
        offs[E_NUM] = run;
    }
    __syncthreads();
    int run[E_NUM];
    #pragma unroll
    for (int i = 0; i < E_NUM; ++i) run[i] = base[i] + cnt[tid][i];
    for (int s = tid * 16; s < tid * 16 + 16; ++s) {
        int e2 = top_e[s];
        perm[run[e2]++] = s;
    }
}

// ------- final combine: out[t][h] += sum_k dr[4t+k][h]  (dr pre-weighted) -------
__global__ void combine_kernel(const short* __restrict__ dr, float* __restrict__ out) {
    const int i = blockIdx.x * 256 + threadIdx.x;   // one per 8 cols of a token
    const int t = i >> 8;                            // H_DIM/8 = 256
    const int h8 = (i & 255) * 8;
    float s[8];
    f32x4 o0 = *reinterpret_cast<const f32x4*>(out + (size_t)t * H_DIM + h8);
    f32x4 o1 = *reinterpret_cast<const f32x4*>(out + (size_t)t * H_DIM + h8 + 4);
    #pragma unroll
    for (int j = 0; j < 4; ++j) { s[j] = o0[j]; s[4 + j] = o1[j]; }
    #pragma unroll
    for (int k = 0; k < TOPK; ++k) {
        bf16x8 v = *reinterpret_cast<const bf16x8*>(dr + ((size_t)(t * TOPK + k)) * H_DIM + h8);
        #pragma unroll
        for (int j = 0; j < 8; ++j) s[j] += bf2f(v[j]);
    }
    f32x4 r0 = { s[0], s[1], s[2], s[3] };
    f32x4 r1 = { s[4], s[5], s[6], s[7] };
    *reinterpret_cast<f32x4*>(out + (size_t)t * H_DIM + h8) = r0;
    *reinterpret_cast<f32x4*>(out + (size_t)t * H_DIM + h8 + 4) = r1;
}

// ---- NB=2 gate+up GEMM (R1 engine, nt-innermost grid): 128M x 128N x 32K ----
// blockIdx.x = nt (strip-diverse co-residency -> independent HBM streams),
// blockIdx.y = mt, blockIdx.z = e.  A bf16 [rows][2048]; B1,B2 f32 [2048][ldb].
// Epilogue: act = silu(g)*u -> bf16.
// MODE 0: routed (A gathered via perm; out row = slot). MODE 1: shared (dense).
template<int MODE>
__global__ __launch_bounds__(256, 2) void gemm_gu2(
    const short* __restrict__ A,
    const float* __restrict__ B1g, const float* __restrict__ B2g, int ldb,
    short* __restrict__ Act,
    const int* __restrict__ perm, const int* __restrict__ offs)
{
    constexpr int KP = 40;
    __shared__ short As[2][128 * KP];          // 20 KB
    __shared__ short Bs[2][2 * 128 * KP];      // 40 KB
    __shared__ int   rows_a[128];
    __shared__ int   rows_o[128];

    const int tid = threadIdx.x;
    const int nt = blockIdx.x, mt = blockIdx.y, e = blockIdx.z;

    int off = 0, cnt = T_NUM;
    const float* B1 = B1g;
    const float* B2 = B2g;
    if constexpr (MODE == 0) {
        off = offs[e]; cnt = offs[e + 1] - off;
        if (mt * 128 >= cnt) return;
        B1 = B1g + (size_t)e * H_DIM * I_DIM;
        B2 = B2g + (size_t)e * H_DIM * I_DIM;
    }

    if (tid < 128) {
        const int gm = mt * 128 + tid;
        if constexpr (MODE == 0) {
            int s = perm[off + (gm < cnt ? gm : cnt - 1)];
            rows_a[tid] = s >> 2; rows_o[tid] = s;
        } else {
            rows_a[tid] = gm; rows_o[tid] = gm;
        }
    }
    __syncthreads();

    int raReg[2];
    #pragma unroll
    for (int it = 0; it < 2; ++it) raReg[it] = rows_a[it * 64 + (tid >> 2)];

    bf16x8 aReg[2];
    float  bReg[2][4][4];

    auto gload = [&](int kt) {
        const int k0 = kt * 32;
        #pragma unroll
        for (int it = 0; it < 2; ++it) {
            const int q = it * 256 + tid;
            const int ko = (q & 3) * 8;
            aReg[it] = *reinterpret_cast<const bf16x8*>(A + (size_t)raReg[it] * H_DIM + k0 + ko);
        }
        #pragma unroll
        for (int it = 0; it < 4; ++it) {
            const int q = it * 256 + tid;
            const int n = q & 127, kb = (q >> 7) * 4;
            const float* p1 = B1 + (size_t)(k0 + kb) * ldb + (size_t)nt * 128 + n;
            #pragma unroll
            for (int dk = 0; dk < 4; ++dk) bReg[0][it][dk] = p1[(size_t)dk * ldb];
            const float* p2 = B2 + (size_t)(k0 + kb) * ldb + (size_t)nt * 128 + n;
            #pragma unroll
            for (int dk = 0; dk < 4; ++dk) bReg[1][it][dk] = p2[(size_t)dk * ldb];
        }
    };

    auto swrite = [&](int buf) {
        #pragma unroll
        for (int it = 0; it < 2; ++it) {
            const int q = it * 256 + tid;
            const int m = q >> 2, ko = (q & 3) * 8;
            *reinterpret_cast<bf16x8*>(&As[buf][m * KP + ko]) = aReg[it];
        }
        #pragma unroll
        for (int it = 0; it < 4; ++it) {
            const int q = it * 256 + tid;
            const int n = q & 127, kb = (q >> 7) * 4;
            #pragma unroll
            for (int mat = 0; mat < 2; ++mat) {
                s16x4 v = { f2bf(bReg[mat][it][0]), f2bf(bReg[mat][it][1]),
                            f2bf(bReg[mat][it][2]), f2bf(bReg[mat][it][3]) };
                *reinterpret_cast<s16x4*>(&Bs[buf][(mat * 128 + n) * KP + kb]) = v;
            }
        }
    };

    f32x4 acc1[4][4], acc2[4][4];
    #pragma unroll
    for (int i = 0; i < 4; ++i)
        #pragma unroll
        for (int j = 0; j < 4; ++j) { acc1[i][j] = (f32x4)0.f; acc2[i][j] = (f32x4)0.f; }

    const int lane = tid & 63;
    const int wr = (tid >> 6) >> 1, wc = (tid >> 6) & 1;
    const int lrow = lane & 15;
    const int lko = (lane >> 4) * 8;

    auto compute = [&](int buf) {
        bf16x8 af[4];
        #pragma unroll
        for (int mi = 0; mi < 4; ++mi)
            af[mi] = *reinterpret_cast<const bf16x8*>(&As[buf][(wr * 64 + mi * 16 + lrow) * KP + lko]);
        #pragma unroll
        for (int ni = 0; ni < 4; ++ni) {
            const int brow = (wc * 64 + ni * 16 + lrow) * KP + lko;
            bf16x8 b1 = *reinterpret_cast<const bf16x8*>(&Bs[buf][brow]);
            #pragma unroll
            for (int mi = 0; mi < 4; ++mi)
                acc1[mi][ni] = __builtin_amdgcn_mfma_f32_16x16x32_bf16(af[mi], b1, acc1[mi][ni], 0, 0, 0);
            bf16x8 b2 = *reinterpret_cast<const bf16x8*>(&Bs[buf][128 * KP + brow]);
            #pragma unroll
            for (int mi = 0; mi < 4; ++mi)
                acc2[mi][ni] = __builtin_amdgcn_mfma_f32_16x16x32_bf16(af[mi], b2, acc2[mi][ni], 0, 0, 0);
        }
    };

    const int NK = H_DIM / 32;
    gload(0);
    int cur = 0;
    for (int kt = 0; kt < NK; ++kt) {
        swrite(cur);
        __syncthreads();
        if (kt + 1 < NK) gload(kt + 1);
        compute(cur);
        cur ^= 1;
    }

    #pragma unroll
    for (int mi = 0; mi < 4; ++mi) {
        #pragma unroll
        for (int j = 0; j < 4; ++j) {
            const int ml = wr * 64 + mi * 16 + (lane >> 4) * 4 + j;
            const int gm = mt * 128 + ml;
            if constexpr (MODE == 0) { if (gm >= cnt) continue; }
            const int orow = rows_o[ml];
            #pragma unroll
            for (int ni = 0; ni < 4; ++ni) {
                const int n = nt * 128 + wc * 64 + ni * 16 + (lane & 15);
                const float g = acc1[mi][ni][j];
                const float u = acc2[mi][ni][j];
                Act[(size_t)orow * ldb + n] = f2bf(g / (1.f + __expf(-g)) * u);
            }
        }
    }
}

// ---- NB=1 down GEMM (R5 engine, nt-innermost grid): 128M x 128N x 32K ----
// A bf16 [rows][KD]; B f32 [KD][2048].
// MODE 2: routed (A=act_r gathered; dr[slot] = w*v bf16). MODE 3: shared (f32 out).
template<int MODE>
__global__ __launch_bounds__(256, 3) void gemm_dn1(
    const short* __restrict__ A,
    const float* __restrict__ B_,
    void* __restrict__ Outv,
    const int* __restrict__ perm, const int* __restrict__ offs,
    const float* __restrict__ top_w)
{
    constexpr int KD = (MODE == 2) ? I_DIM : SHI_DIM;
    constexpr int KP = 40;
    __shared__ short As[2][128 * KP];     // 20 KB
    __shared__ short Bs[2][128 * KP];     // 20 KB
    __shared__ int   rows_a[128];
    __shared__ int   rows_o[128];
    __shared__ float w_m[128];

    const int tid = threadIdx.x;
    const int nt = blockIdx.x, mt = blockIdx.y, e = blockIdx.z;

    int off = 0, cnt = T_NUM;
    const float* B = B_;
    if constexpr (MODE == 2) {
        off = offs[e]; cnt = offs[e + 1] - off;
        if (mt * 128 >= cnt) return;
        B = B_ + (size_t)e * I_DIM * H_DIM;
    }
    const int ncol = nt * 128;

    if (tid < 128) {
        const int gm = mt * 128 + tid;
        if constexpr (MODE == 2) {
            int s = perm[off + (gm < cnt ? gm : cnt - 1)];
            rows_a[tid] = s; rows_o[tid] = s; w_m[tid] = top_w[s];
        } else {
            rows_a[tid] = gm; rows_o[tid] = gm; w_m[tid] = 1.f;
        }
    }
    __syncthreads();

    int raReg[2];
    #pragma unroll
    for (int it = 0; it < 2; ++it) raReg[it] = rows_a[it * 64 + (tid >> 2)];

    bf16x8 aReg[2];
    float  bReg[4][4];

    auto gload = [&](int kt) {
        const int k0 = kt * 32;
        #pragma unroll
        for (int it = 0; it < 2; ++it) {
            const int q = it * 256 + tid;
            const int ko = (q & 3) * 8;
            aReg[it] = *reinterpret_cast<const bf16x8*>(A + (size_t)raReg[it] * KD + k0 + ko);
        }
        #pragma unroll
        for (int it = 0; it < 4; ++it) {
            const int q = it * 256 + tid;
            const int n = q & 127, kb = (q >> 7) * 4;
            const float* p1 = B + (size_t)(k0 + kb) * H_DIM + ncol + n;
            #pragma unroll
            for (int dk = 0; dk < 4; ++dk) bReg[it][dk] = p1[(size_t)dk * H_DIM];
        }
    };

    auto swrite = [&](int buf) {
        #pragma unroll
        for (int it = 0; it < 2; ++it) {
            const int q = it * 256 + tid;
            const int m = q >> 2, ko = (q & 3) * 8;
            *reinterpret_cast<bf16x8*>(&As[buf][m * KP + ko]) = aReg[it];
        }
        #pragma unroll
        for (int it = 0; it < 4; ++it) {
            const int q = it * 256 + tid;
            const int n = q & 127, kb = (q >> 7) * 4;
            s16x4 v = { f2bf(bReg[it][0]), f2bf(bReg[it][1]), f2bf(bReg[it][2]), f2bf(bReg[it][3]) };
            *reinterpret_cast<s16x4*>(&Bs[buf][n * KP + kb]) = v;
        }
    };

    f32x4 acc[4][4];
    #pragma unroll
    for (int i = 0; i < 4; ++i)
        #pragma unroll
        for (int j = 0; j < 4; ++j) acc[i][j] = (f32x4)0.f;

    const int lane = tid & 63;
    const int wr = (tid >> 6) >> 1, wc = (tid >> 6) & 1;
    const int lrow = lane & 15;
    const int lko = (lane >> 4) * 8;

    auto compute = [&](int buf) {
        bf16x8 af[4];
        #pragma unroll
        for (int mi = 0; mi < 4; ++mi)
            af[mi] = *reinterpret_cast<const bf16x8*>(&As[buf][(wr * 64 + mi * 16 + lrow) * KP + lko]);
        #pragma unroll
        for (int ni = 0; ni < 4; ++ni) {
            bf16x8 bfr = *reinterpret_cast<const bf16x8*>(&Bs[buf][(wc * 64 + ni * 16 + lrow) * KP + lko]);
            #pragma unroll
            for (int mi = 0; mi < 4; ++mi)
                acc[mi][ni] = __builtin_amdgcn_mfma_f32_16x16x32_bf16(af[mi], bfr, acc[mi][ni], 0, 0, 0);
        }
    };

    const int NK = KD / 32;
    gload(0);
    int cur = 0;
    for (int kt = 0; kt < NK; ++kt) {
        swrite(cur);
        __syncthreads();
        if (kt + 1 < NK) gload(kt + 1);
        compute(cur);
        cur ^= 1;
    }

    #pragma unroll
    for (int mi = 0; mi < 4; ++mi) {
        #pragma unroll
        for (int j = 0; j < 4; ++j) {
            const int ml = wr * 64 + mi * 16 + (lane >> 4) * 4 + j;
            const int gm = mt * 128 + ml;
            if constexpr (MODE == 2) { if (gm >= cnt) continue; }
            const int orow = rows_o[ml];
            const float wsc = w_m[ml];
            #pragma unroll
            for (int ni = 0; ni < 4; ++ni) {
                const int n = ncol + wc * 64 + ni * 16 + (lane & 15);
                const float v = acc[mi][ni][j];
                if constexpr (MODE == 2) {
                    ((short*)Outv)[(size_t)orow * H_DIM + n] = f2bf(v * wsc);
                } else {
                    ((float*)Outv)[(size_t)orow * H_DIM + n] = v;
                }
            }
        }
    }
}

extern "C" void kernel_launch(void* const* d_in, const int* in_sizes, int n_in,
                              void* d_out, int out_size, void* d_ws, size_t ws_size,
                              hipStream_t stream) {
    const float* x     = (const float*)d_in[0];
    const float* wgate = (const float*)d_in[1];
    const float* wg    = (const float*)d_in[2];
    const float* wu    = (const float*)d_in[3];
    const float* wd    = (const float*)d_in[4];
    const float* sg    = (const float*)d_in[5];
    const float* su    = (const float*)d_in[6];
    const float* sd    = (const float*)d_in[7];
    float* out = (float*)d_out;

    uintptr_t p = (uintptr_t)d_ws;
    auto alloc = [&](size_t bytes) {
        p = (p + 255) & ~(uintptr_t)255;
        void* r = (void*)p; p += bytes; return r;
    };
    int*   top_e = (int*)alloc((size_t)T_NUM * TOPK * sizeof(int));
    float* top_w = (float*)alloc((size_t)T_NUM * TOPK * sizeof(float));
    int*   offs  = (int*)alloc((E_NUM + 1) * sizeof(int));
    int*   perm  = (int*)alloc((size_t)T_NUM * TOPK * sizeof(int));
    short* xb    = (short*)alloc((size_t)T_NUM * H_DIM * 2);
    short* act_r = (short*)alloc((size_t)T_NUM * TOPK * I_DIM * 2);   // 11.5 MB
    short* act_s = (short*)alloc((size_t)T_NUM * SHI_DIM * 2);        // 5.8 MB
    short* dr    = (short*)alloc((size_t)T_NUM * TOPK * H_DIM * 2);   // 16.8 MB

    router_kernel<<<T_NUM, 256, 0, stream>>>(x, wgate, top_e, top_w, xb);
    perm_kernel<<<1, 256, 0, stream>>>(top_e, offs, perm);

    // shared gate+up+silu (fused): grid (22, 8)
    gemm_gu2<1><<<dim3(SHI_DIM / 128, T_NUM / 128, 1), 256, 0, stream>>>(
        xb, sg, su, SHI_DIM, act_s, nullptr, nullptr);
    // shared down -> out f32 (plain stores init out): grid (16, 8)
    gemm_dn1<3><<<dim3(H_DIM / 128, T_NUM / 128, 1), 256, 0, stream>>>(
        act_s, sd, out, nullptr, nullptr, nullptr);

    // routed gate+up+silu per expert: grid (11, 8, 16)
    gemm_gu2<0><<<dim3(I_DIM / 128, T_NUM / 128, E_NUM), 256, 0, stream>>>(
        xb, wg, wu, I_DIM, act_r, perm, offs);
    // routed down per expert -> dr (pre-weighted): grid (16, 8, 16)
    gemm_dn1<2><<<dim3(H_DIM / 128, T_NUM / 128, E_NUM), 256, 0, stream>>>(
        act_r, wd, dr, perm, offs, top_w);
    // out[t] += sum_k dr[4t+k]
    combine_kernel<<<T_NUM * H_DIM / 8 / 256, 256, 0, stream>>>(dr, out);
}